// Round 1
// baseline (729.539 us; speedup 1.0000x reference)
//
#include <hip/hip_runtime.h>
#include <hip/hip_bf16.h>

// Problem constants (fixed by the reference)
constexpr int N_NODES = 50000;
constexpr int N_EDGES = 800000;
constexpr int R_REL   = 8;
constexpr int BASES   = 4;
constexpr int D       = 256;                 // DIN = DH = DOUT
constexpr int KZ      = BASES * D;           // 1024: basis-space aggregate
constexpr int KT      = KZ + D;              // 1280: + self block
// A-matrix layout for GEMM: k < 1024 -> zA[n][k], k = col*4 + b (interleaved)
//                           k >= 1024 -> self feature col = k - 1024 (from xb/h)

typedef __attribute__((ext_vector_type(8))) short bf16x8;
typedef __attribute__((ext_vector_type(4))) float f32x4;
typedef __attribute__((ext_vector_type(4))) int   i32x4;

__device__ inline float bfu_lo(unsigned u) { return __uint_as_float(u << 16); }
__device__ inline float bfu_hi(unsigned u) { return __uint_as_float(u & 0xFFFF0000u); }
__device__ inline unsigned short f2bu(float f) {
  __hip_bfloat16 h = __float2bfloat16(f);
  return *reinterpret_cast<unsigned short*>(&h);
}
// final fp32 output: nontemporal (never re-read)
__device__ inline void store_out(float* p, float v) { __builtin_nontemporal_store(v, p); }
// h (bf16): re-read as gather source next layer -> keep cached
__device__ inline void store_out(__hip_bfloat16* p, float v) { *p = __float2bfloat16(v); }

// async 16B global -> LDS (wave-uniform lds base + lane*16)
__device__ inline void gload_lds16(void* lds, const void* g) {
  __builtin_amdgcn_global_load_lds(
      (const __attribute__((address_space(1))) unsigned*)g,
      (__attribute__((address_space(3))) unsigned*)lds, 16, 0, 0);
}

// ---------------------------------------------------------------------------
// 1. Per-(dst, relation) edge counts
// ---------------------------------------------------------------------------
__global__ __launch_bounds__(256) void count_kernel(
    const int* __restrict__ ei, const int* __restrict__ et,
    int* __restrict__ cnt) {
  int e = blockIdx.x * 256 + threadIdx.x;
  if (e < N_EDGES) {
    int dst = ei[N_EDGES + e];
    int rt  = et[e];
    atomicAdd(&cnt[dst * R_REL + rt], 1);
  }
}

// ---------------------------------------------------------------------------
// 2. Exclusive scan of per-node degree (3-phase)
// ---------------------------------------------------------------------------
__global__ __launch_bounds__(256) void scan_phaseA(
    const int* __restrict__ cnt, int* __restrict__ bsum) {
  __shared__ int sd[256];
  int tid = threadIdx.x;
  int n = blockIdx.x * 256 + tid;
  int d = 0;
  if (n < N_NODES) {
#pragma unroll
    for (int r = 0; r < R_REL; r++) d += cnt[n * R_REL + r];
  }
  sd[tid] = d;
  __syncthreads();
  for (int off = 128; off > 0; off >>= 1) {
    if (tid < off) sd[tid] += sd[tid + off];
    __syncthreads();
  }
  if (tid == 0) bsum[blockIdx.x] = sd[0];
}

__global__ __launch_bounds__(256) void scan_phaseB(
    const int* __restrict__ bsum, int* __restrict__ boff,
    int* __restrict__ estart, int NB) {
  __shared__ int sd[256];
  int tid = threadIdx.x;
  int v = (tid < NB) ? bsum[tid] : 0;
  sd[tid] = v;
  __syncthreads();
  for (int off = 1; off < 256; off <<= 1) {
    int t = (tid >= off) ? sd[tid - off] : 0;
    __syncthreads();
    sd[tid] += t;
    __syncthreads();
  }
  if (tid < NB) boff[tid] = sd[tid] - v;
  if (tid == 0) estart[N_NODES] = N_EDGES;
}

__global__ __launch_bounds__(256) void scan_phaseC(
    const int* __restrict__ cnt, const int* __restrict__ boff,
    int* __restrict__ estart) {
  __shared__ int sd[256];
  int tid = threadIdx.x;
  int n = blockIdx.x * 256 + tid;
  int d = 0;
  if (n < N_NODES) {
#pragma unroll
    for (int r = 0; r < R_REL; r++) d += cnt[n * R_REL + r];
  }
  sd[tid] = d;
  __syncthreads();
  for (int off = 1; off < 256; off <<= 1) {
    int t = (tid >= off) ? sd[tid - off] : 0;
    __syncthreads();
    sd[tid] += t;
    __syncthreads();
  }
  if (n < N_NODES) estart[n] = boff[blockIdx.x] + sd[tid] - d;
}

// ---------------------------------------------------------------------------
// 3. Bucket edges by dst: packed = src | (rt << 20)
// ---------------------------------------------------------------------------
__global__ __launch_bounds__(256) void bucket_kernel(
    const int* __restrict__ ei, const int* __restrict__ et,
    const int* __restrict__ estart, int* __restrict__ cursor,
    int* __restrict__ packed) {
  int e = blockIdx.x * 256 + threadIdx.x;
  if (e < N_EDGES) {
    int src = ei[e];
    int dst = ei[N_EDGES + e];
    int rt  = et[e];
    int pos = estart[dst] + atomicAdd(&cursor[dst], 1);
    packed[pos] = src | (rt << 20);
  }
}

// ---------------------------------------------------------------------------
// 4. x (fp32) -> bf16, packed as uint pairs: x2[n*128 + c] holds cols 2c,2c+1
// ---------------------------------------------------------------------------
__global__ __launch_bounds__(256) void convert_kernel(
    const float* __restrict__ x, unsigned* __restrict__ x2) {
  int idx = blockIdx.x * 256 + threadIdx.x;  // over N*128
  if (idx < N_NODES * 128) {
    float2 v = *(const float2*)(x + (size_t)idx * 2);
    x2[idx] = (unsigned)f2bu(v.x) | ((unsigned)f2bu(v.y) << 16);
  }
}

// ---------------------------------------------------------------------------
// 4b. Precompute per-(node,relation) basis weights: wtab[n*8+r] = comp[r][:]/cnt
// ---------------------------------------------------------------------------
__global__ __launch_bounds__(256) void winv_kernel(
    const int* __restrict__ cnt, const float* __restrict__ comp,
    float4* __restrict__ wtab) {
  int idx = blockIdx.x * 256 + threadIdx.x;  // n*8 + r
  if (idx < N_NODES * R_REL) {
    int r = idx & 7;
    int c = cnt[idx];
    float inv = 1.0f / (float)(c > 0 ? c : 1);
    float4 w;
    w.x = comp[r * BASES + 0] * inv;
    w.y = comp[r * BASES + 1] * inv;
    w.z = comp[r * BASES + 2] * inv;
    w.w = comp[r * BASES + 3] * inv;
    wtab[idx] = w;
  }
}

// ---------------------------------------------------------------------------
// 5. Weight build: WT[o][k] bf16 (transposed). Coalesced reads, LDS transpose.
// ---------------------------------------------------------------------------
__global__ __launch_bounds__(256) void make_w_kernel(
    const float* __restrict__ basis, const float* __restrict__ root,
    __hip_bfloat16* __restrict__ WT) {
  __shared__ __hip_bfloat16 tile[64][256];
  int k0 = blockIdx.x * 64;
  int tid = threadIdx.x;
#pragma unroll 4
  for (int r = 0; r < 64; r++) {
    int k = k0 + r;
    const float* srow = (k < KZ)
        ? basis + ((size_t)(k & 3) * D + (k >> 2)) * D
        : root + (size_t)(k - KZ) * D;
    tile[r][tid] = __float2bfloat16(srow[tid]);
  }
  __syncthreads();
  __hip_bfloat16* dst = WT + (size_t)tid * KT + k0;
#pragma unroll
  for (int c = 0; c < 8; c++) {
    union { short s[8]; int4 v; } u;
#pragma unroll
    for (int r = 0; r < 8; r++)
      u.s[r] = *reinterpret_cast<short*>(&tile[c * 8 + r][tid]);
    *(int4*)(dst + c * 8) = u.v;
  }
}

// ---------------------------------------------------------------------------
// 6. Aggregate into basis space. WAVE per node, persistent waves with
//    static-first + atomic work queue (fixes Poisson-degree imbalance).
//    Lane owns cols {4*lane..4*lane+3} x 4 bases. float2 math -> v_pk_fma_f32.
//    zA written nontemporal so streaming output doesn't evict the gather
//    working set (x2/h, 25.6 MB, LLC-resident) out of the Infinity Cache.
// ---------------------------------------------------------------------------
constexpr int AGG_BLOCKS = 2048;             // 8 blocks/CU x 4 waves = full CU
constexpr int AGG_WAVES  = AGG_BLOCKS * 4;   // 8192
constexpr int GRAB       = 4;                // nodes per work grab
constexpr int NSTATIC    = AGG_WAVES * GRAB; // 32768 statically assigned

__device__ inline float2 pfma(float s, float2 a, float2 c) {
  c.x = fmaf(s, a.x, c.x);
  c.y = fmaf(s, a.y, c.y);
  return c;
}

__device__ inline void edge_fma(float2 acc[BASES][2], uint2 v, float4 w) {
  float2 a01 = make_float2(bfu_lo(v.x), bfu_hi(v.x));
  float2 a23 = make_float2(bfu_lo(v.y), bfu_hi(v.y));
  acc[0][0] = pfma(w.x, a01, acc[0][0]); acc[0][1] = pfma(w.x, a23, acc[0][1]);
  acc[1][0] = pfma(w.y, a01, acc[1][0]); acc[1][1] = pfma(w.y, a23, acc[1][1]);
  acc[2][0] = pfma(w.z, a01, acc[2][0]); acc[2][1] = pfma(w.z, a23, acc[2][1]);
  acc[3][0] = pfma(w.w, a01, acc[3][0]); acc[3][1] = pfma(w.w, a23, acc[3][1]);
}

__global__ __launch_bounds__(256) void aggregate_kernel(
    const unsigned* __restrict__ x2,   // bf16 features as uint pairs [N][128]
    const int* __restrict__ packed,
    const int* __restrict__ estart,
    const float4* __restrict__ wtab,   // [N*8] per-(node,rel) basis weights
    __hip_bfloat16* __restrict__ zA,   // [N][KZ]
    int* __restrict__ wq)              // work-queue cursor (init 0)
{
  int tid  = threadIdx.x;
  int wave = tid >> 6, lane = tid & 63;
  int nbase = (blockIdx.x * 4 + wave) * GRAB;  // static first batch

  while (nbase < N_NODES) {
    int nend = nbase + GRAB;
    if (nend > N_NODES) nend = N_NODES;

    for (int n = nbase; n < nend; n++) {
      float2 acc[BASES][2] = {};
      int s = estart[n], e = estart[n + 1];
      const float4* wt = wtab + (size_t)n * R_REL;

      int i = s;
      for (; i + 4 <= e; i += 4) {
        int p0 = packed[i];
        int p1 = packed[i + 1];
        int p2 = packed[i + 2];
        int p3 = packed[i + 3];
        // 4 independent gathers in flight
        uint2 v0 = *(const uint2*)(x2 + (size_t)(p0 & 0xFFFFF) * 128 + lane * 2);
        uint2 v1 = *(const uint2*)(x2 + (size_t)(p1 & 0xFFFFF) * 128 + lane * 2);
        uint2 v2 = *(const uint2*)(x2 + (size_t)(p2 & 0xFFFFF) * 128 + lane * 2);
        uint2 v3 = *(const uint2*)(x2 + (size_t)(p3 & 0xFFFFF) * 128 + lane * 2);
        float4 w0 = wt[p0 >> 20];
        float4 w1 = wt[p1 >> 20];
        float4 w2 = wt[p2 >> 20];
        float4 w3 = wt[p3 >> 20];
        edge_fma(acc, v0, w0);
        edge_fma(acc, v1, w1);
        edge_fma(acc, v2, w2);
        edge_fma(acc, v3, w3);
      }
      for (; i < e; i++) {
        int p = packed[i];
        uint2 v = *(const uint2*)(x2 + (size_t)(p & 0xFFFFF) * 128 + lane * 2);
        float4 w = wt[p >> 20];
        edge_fma(acc, v, w);
      }

      // store: k = (4*lane+j)*4 + b = 16*lane + 4*j + b -> 32 contiguous bytes
      union { short s[8]; i32x4 v; } u0, u1;
#pragma unroll
      for (int b = 0; b < BASES; b++) {
        u0.s[b]     = (short)f2bu(acc[b][0].x);
        u0.s[4 + b] = (short)f2bu(acc[b][0].y);
        u1.s[b]     = (short)f2bu(acc[b][1].x);
        u1.s[4 + b] = (short)f2bu(acc[b][1].y);
      }
      __hip_bfloat16* zrow = zA + (size_t)n * KZ;
      __builtin_nontemporal_store(u0.v, (i32x4*)(zrow + 16 * lane));
      __builtin_nontemporal_store(u1.v, (i32x4*)(zrow + 16 * lane + 8));
    }

    int idx0 = 0;
    if (lane == 0) idx0 = atomicAdd(wq, 1);
    int idx = __builtin_amdgcn_readfirstlane(idx0);
    nbase = NSTATIC + idx * GRAB;
  }
}

// ---------------------------------------------------------------------------
// 7. GEMM: C[M,256] = A[M,1280](bf16) @ WT^T + bias. BM=128, BN=256 (full N,
//    A read once), 512 threads / 8 waves, BK=32, global_load_lds staging.
//    A is split: k<1024 from Az ([M][1024] aggregate), k>=1024 from Aself
//    ([M][256] node features) -- saves writing/reading the self copy.
// ---------------------------------------------------------------------------
#define BM 128
#define BN 256
#define BK 32

template <bool RELU, typename OutT>
__global__ __launch_bounds__(512) void gemm_kernel(
    const __hip_bfloat16* __restrict__ Az,     // [M, KZ]
    const __hip_bfloat16* __restrict__ Aself,  // [M, D]
    const __hip_bfloat16* __restrict__ Bt,     // [256, KT] (transposed weights)
    const float* __restrict__ bias, OutT* __restrict__ C, int M) {
  __shared__ __align__(16) __hip_bfloat16 As[BM * BK];  // 8 KB
  __shared__ __align__(16) __hip_bfloat16 Bs[BN * BK];  // 16 KB
  int tid = threadIdx.x;
  int m0 = blockIdx.x * BM;
  int wave = tid >> 6, lane = tid & 63;
  int wm = wave & 1, wn = wave >> 1;   // 2 x 4 wave grid, 64x64 tiles
  int l15 = lane & 15, quad = lane >> 4;

  // staging geometry: lane covers row = base + lane/4, col (lane&3)*8;
  // LDS dest = wave-uniform base + lane*16 B
  int colS = (lane & 3) * 8;
  int rowA = wave * 16 + (lane >> 2);           // 0..127 across 8 waves
  int grA  = min(m0 + rowA, M - 1);             // clamp; epilogue masks tail
  const __hip_bfloat16* gAz = Az + (size_t)grA * KZ + colS;
  const __hip_bfloat16* gAs = Aself + (size_t)grA * D + colS;
  const __hip_bfloat16* gB0 = Bt + (size_t)(wave * 32 + (lane >> 2)) * KT + colS;
  const __hip_bfloat16* gB1 = gB0 + 16 * KT;
  __hip_bfloat16* lA  = As + wave * 512;
  __hip_bfloat16* lB0 = Bs + wave * 1024;
  __hip_bfloat16* lB1 = Bs + wave * 1024 + 512;

  f32x4 acc[4][4] = {};

  for (int k0 = 0; k0 < KT; k0 += BK) {
    const __hip_bfloat16* srcA = (k0 < KZ) ? (gAz + k0) : (gAs + (k0 - KZ));
    gload_lds16(lA, srcA);
    gload_lds16(lB0, gB0 + k0);
    gload_lds16(lB1, gB1 + k0);
    __syncthreads();

    bf16x8 af[4], bfr[4];
#pragma unroll
    for (int mt = 0; mt < 4; mt++)
      af[mt] = *(const bf16x8*)(As + (wm * 64 + mt * 16 + l15) * BK + quad * 8);
#pragma unroll
    for (int nt = 0; nt < 4; nt++)
      bfr[nt] = *(const bf16x8*)(Bs + (wn * 64 + nt * 16 + l15) * BK + quad * 8);
#pragma unroll
    for (int mt = 0; mt < 4; mt++)
#pragma unroll
      for (int nt = 0; nt < 4; nt++)
        acc[mt][nt] = __builtin_amdgcn_mfma_f32_16x16x32_bf16(
            af[mt], bfr[nt], acc[mt][nt], 0, 0, 0);
    __syncthreads();
  }

  // epilogue: C/D layout col = lane&15, row = quad*4 + reg
#pragma unroll
  for (int nt = 0; nt < 4; nt++) {
    int cg = wn * 64 + nt * 16 + l15;
    float bv = bias[cg];
#pragma unroll
    for (int mt = 0; mt < 4; mt++) {
#pragma unroll
      for (int r = 0; r < 4; r++) {
        int rg = m0 + wm * 64 + mt * 16 + quad * 4 + r;
        if (rg < M) {
          float v = acc[mt][nt][r] + bv;
          if (RELU) v = fmaxf(v, 0.f);
          store_out(C + (size_t)rg * D + cg, v);
        }
      }
    }
  }
}

// ---------------------------------------------------------------------------
// Launch
// ---------------------------------------------------------------------------
static inline char* carve(char*& p, size_t bytes) {
  char* r = p;
  p += (bytes + 255) & ~(size_t)255;
  return r;
}

extern "C" void kernel_launch(void* const* d_in, const int* in_sizes, int n_in,
                              void* d_out, int out_size, void* d_ws,
                              size_t ws_size, hipStream_t stream) {
  const float* x      = (const float*)d_in[0];
  const int*   ei     = (const int*)d_in[1];
  const int*   et     = (const int*)d_in[2];
  const float* basis1 = (const float*)d_in[3];
  const float* comp1  = (const float*)d_in[4];
  const float* root1  = (const float*)d_in[5];
  const float* bias1  = (const float*)d_in[6];
  const float* basis2 = (const float*)d_in[7];
  const float* comp2  = (const float*)d_in[8];
  const float* root2  = (const float*)d_in[9];
  const float* bias2  = (const float*)d_in[10];
  float* out = (float*)d_out;

  char* ws = (char*)d_ws;
  int* cnt    = (int*)carve(ws, (size_t)N_NODES * R_REL * 4);
  int* estart = (int*)carve(ws, (size_t)(N_NODES + 1) * 4);
  int* cursor = (int*)carve(ws, (size_t)N_NODES * 4);
  int* bsum   = (int*)carve(ws, 256 * 4);
  int* boff   = (int*)carve(ws, 256 * 4);
  int* wq     = (int*)carve(ws, 2 * 4);
  int* packed = (int*)carve(ws, (size_t)N_EDGES * 4);
  float4* wtab1 = (float4*)carve(ws, (size_t)N_NODES * R_REL * 16);
  float4* wtab2 = (float4*)carve(ws, (size_t)N_NODES * R_REL * 16);
  __hip_bfloat16* WT1 = (__hip_bfloat16*)carve(ws, (size_t)D * KT * 2);
  __hip_bfloat16* WT2 = (__hip_bfloat16*)carve(ws, (size_t)D * KT * 2);
  unsigned* xb = (unsigned*)carve(ws, (size_t)N_NODES * D * 2);   // bf16 x
  __hip_bfloat16* h = (__hip_bfloat16*)carve(ws, (size_t)N_NODES * D * 2);
  __hip_bfloat16* zA = (__hip_bfloat16*)carve(ws, (size_t)N_NODES * KZ * 2);

  const int NB = (N_NODES + 255) / 256;   // 196
  const int EB = (N_EDGES + 255) / 256;   // 3125
  const int CB = (N_NODES * 128 + 255) / 256;
  const int WB = (N_NODES * R_REL + 255) / 256;

  hipMemsetAsync(cnt, 0, (size_t)N_NODES * R_REL * 4, stream);
  hipMemsetAsync(cursor, 0, (size_t)N_NODES * 4, stream);
  hipMemsetAsync(wq, 0, 2 * 4, stream);

  count_kernel<<<EB, 256, 0, stream>>>(ei, et, cnt);
  scan_phaseA<<<NB, 256, 0, stream>>>(cnt, bsum);
  scan_phaseB<<<1, 256, 0, stream>>>(bsum, boff, estart, NB);
  scan_phaseC<<<NB, 256, 0, stream>>>(cnt, boff, estart);
  bucket_kernel<<<EB, 256, 0, stream>>>(ei, et, estart, cursor, packed);

  convert_kernel<<<CB, 256, 0, stream>>>(x, xb);
  winv_kernel<<<WB, 256, 0, stream>>>(cnt, comp1, wtab1);
  winv_kernel<<<WB, 256, 0, stream>>>(cnt, comp2, wtab2);
  make_w_kernel<<<KT / 64, 256, 0, stream>>>(basis1, root1, WT1);
  make_w_kernel<<<KT / 64, 256, 0, stream>>>(basis2, root2, WT2);

  dim3 ggrid((N_NODES + BM - 1) / BM, 1);  // 391 blocks, full N per block

  // Layer 1
  aggregate_kernel<<<AGG_BLOCKS, 256, 0, stream>>>(xb, packed, estart, wtab1,
                                                   zA, wq);
  gemm_kernel<true, __hip_bfloat16><<<ggrid, 512, 0, stream>>>(
      zA, (const __hip_bfloat16*)xb, WT1, bias1, h, N_NODES);

  // Layer 2 (h is bf16 [N][256] — same packed-uint view as xb)
  aggregate_kernel<<<AGG_BLOCKS, 256, 0, stream>>>((const unsigned*)h, packed,
                                                   estart, wtab2, zA, wq + 1);
  gemm_kernel<false, float><<<ggrid, 512, 0, stream>>>(
      zA, h, WT2, bias2, out, N_NODES);
}

// Round 2
// 491.343 us; speedup vs baseline: 1.4848x; 1.4848x over previous
//
#include <hip/hip_runtime.h>
#include <hip/hip_bf16.h>

// Problem constants (fixed by the reference)
constexpr int N_NODES = 50000;
constexpr int N_EDGES = 800000;
constexpr int R_REL   = 8;
constexpr int BASES   = 4;
constexpr int D       = 256;                 // DIN = DH = DOUT
constexpr int KZ      = BASES * D;           // 1024: basis-space aggregate
constexpr int KT      = KZ + D;              // 1280: + self block
// A-matrix layout for GEMM: k < 1024 -> zA[n][k], k = col*4 + b (interleaved)
//                           k >= 1024 -> self feature col = k - 1024 (from xb/h)

typedef __attribute__((ext_vector_type(8))) short bf16x8;
typedef __attribute__((ext_vector_type(4))) float f32x4;

__device__ inline float bfu_lo(unsigned u) { return __uint_as_float(u << 16); }
__device__ inline float bfu_hi(unsigned u) { return __uint_as_float(u & 0xFFFF0000u); }
__device__ inline unsigned short f2bu(float f) {
  __hip_bfloat16 h = __float2bfloat16(f);
  return *reinterpret_cast<unsigned short*>(&h);
}
__device__ inline void store_out(float* p, float v) { *p = v; }
__device__ inline void store_out(__hip_bfloat16* p, float v) { *p = __float2bfloat16(v); }

// async 16B global -> LDS (wave-uniform lds base + lane*16)
__device__ inline void gload_lds16(void* lds, const void* g) {
  __builtin_amdgcn_global_load_lds(
      (const __attribute__((address_space(1))) unsigned*)g,
      (__attribute__((address_space(3))) unsigned*)lds, 16, 0, 0);
}

// ---------------------------------------------------------------------------
// 1. Per-(dst, relation) edge counts
// ---------------------------------------------------------------------------
__global__ __launch_bounds__(256) void count_kernel(
    const int* __restrict__ ei, const int* __restrict__ et,
    int* __restrict__ cnt) {
  int e = blockIdx.x * 256 + threadIdx.x;
  if (e < N_EDGES) {
    int dst = ei[N_EDGES + e];
    int rt  = et[e];
    atomicAdd(&cnt[dst * R_REL + rt], 1);
  }
}

// ---------------------------------------------------------------------------
// 2. Exclusive scan of per-node degree (3-phase)
// ---------------------------------------------------------------------------
__global__ __launch_bounds__(256) void scan_phaseA(
    const int* __restrict__ cnt, int* __restrict__ bsum) {
  __shared__ int sd[256];
  int tid = threadIdx.x;
  int n = blockIdx.x * 256 + tid;
  int d = 0;
  if (n < N_NODES) {
#pragma unroll
    for (int r = 0; r < R_REL; r++) d += cnt[n * R_REL + r];
  }
  sd[tid] = d;
  __syncthreads();
  for (int off = 128; off > 0; off >>= 1) {
    if (tid < off) sd[tid] += sd[tid + off];
    __syncthreads();
  }
  if (tid == 0) bsum[blockIdx.x] = sd[0];
}

__global__ __launch_bounds__(256) void scan_phaseB(
    const int* __restrict__ bsum, int* __restrict__ boff,
    int* __restrict__ estart, int NB) {
  __shared__ int sd[256];
  int tid = threadIdx.x;
  int v = (tid < NB) ? bsum[tid] : 0;
  sd[tid] = v;
  __syncthreads();
  for (int off = 1; off < 256; off <<= 1) {
    int t = (tid >= off) ? sd[tid - off] : 0;
    __syncthreads();
    sd[tid] += t;
    __syncthreads();
  }
  if (tid < NB) boff[tid] = sd[tid] - v;
  if (tid == 0) estart[N_NODES] = N_EDGES;
}

__global__ __launch_bounds__(256) void scan_phaseC(
    const int* __restrict__ cnt, const int* __restrict__ boff,
    int* __restrict__ estart) {
  __shared__ int sd[256];
  int tid = threadIdx.x;
  int n = blockIdx.x * 256 + tid;
  int d = 0;
  if (n < N_NODES) {
#pragma unroll
    for (int r = 0; r < R_REL; r++) d += cnt[n * R_REL + r];
  }
  sd[tid] = d;
  __syncthreads();
  for (int off = 1; off < 256; off <<= 1) {
    int t = (tid >= off) ? sd[tid - off] : 0;
    __syncthreads();
    sd[tid] += t;
    __syncthreads();
  }
  if (n < N_NODES) estart[n] = boff[blockIdx.x] + sd[tid] - d;
}

// ---------------------------------------------------------------------------
// 3. Bucket edges by dst: packed = src | (rt << 20)
// ---------------------------------------------------------------------------
__global__ __launch_bounds__(256) void bucket_kernel(
    const int* __restrict__ ei, const int* __restrict__ et,
    const int* __restrict__ estart, int* __restrict__ cursor,
    int* __restrict__ packed) {
  int e = blockIdx.x * 256 + threadIdx.x;
  if (e < N_EDGES) {
    int src = ei[e];
    int dst = ei[N_EDGES + e];
    int rt  = et[e];
    int pos = estart[dst] + atomicAdd(&cursor[dst], 1);
    packed[pos] = src | (rt << 20);
  }
}

// ---------------------------------------------------------------------------
// 4. x (fp32) -> bf16, packed as uint pairs: x2[n*128 + c] holds cols 2c,2c+1
// ---------------------------------------------------------------------------
__global__ __launch_bounds__(256) void convert_kernel(
    const float* __restrict__ x, unsigned* __restrict__ x2) {
  int idx = blockIdx.x * 256 + threadIdx.x;  // over N*128
  if (idx < N_NODES * 128) {
    float2 v = *(const float2*)(x + (size_t)idx * 2);
    x2[idx] = (unsigned)f2bu(v.x) | ((unsigned)f2bu(v.y) << 16);
  }
}

// ---------------------------------------------------------------------------
// 4b. Precompute per-(node,relation) basis weights: wtab[n*8+r] = comp[r][:]/cnt
// ---------------------------------------------------------------------------
__global__ __launch_bounds__(256) void winv_kernel(
    const int* __restrict__ cnt, const float* __restrict__ comp,
    float4* __restrict__ wtab) {
  int idx = blockIdx.x * 256 + threadIdx.x;  // n*8 + r
  if (idx < N_NODES * R_REL) {
    int r = idx & 7;
    int c = cnt[idx];
    float inv = 1.0f / (float)(c > 0 ? c : 1);
    float4 w;
    w.x = comp[r * BASES + 0] * inv;
    w.y = comp[r * BASES + 1] * inv;
    w.z = comp[r * BASES + 2] * inv;
    w.w = comp[r * BASES + 3] * inv;
    wtab[idx] = w;
  }
}

// ---------------------------------------------------------------------------
// 5. Weight build: WT[o][k] bf16 (transposed). Coalesced reads, LDS transpose.
// ---------------------------------------------------------------------------
__global__ __launch_bounds__(256) void make_w_kernel(
    const float* __restrict__ basis, const float* __restrict__ root,
    __hip_bfloat16* __restrict__ WT) {
  __shared__ __hip_bfloat16 tile[64][256];
  int k0 = blockIdx.x * 64;
  int tid = threadIdx.x;
#pragma unroll 4
  for (int r = 0; r < 64; r++) {
    int k = k0 + r;
    const float* srow = (k < KZ)
        ? basis + ((size_t)(k & 3) * D + (k >> 2)) * D
        : root + (size_t)(k - KZ) * D;
    tile[r][tid] = __float2bfloat16(srow[tid]);
  }
  __syncthreads();
  __hip_bfloat16* dst = WT + (size_t)tid * KT + k0;
#pragma unroll
  for (int c = 0; c < 8; c++) {
    union { short s[8]; int4 v; } u;
#pragma unroll
    for (int r = 0; r < 8; r++)
      u.s[r] = *reinterpret_cast<short*>(&tile[c * 8 + r][tid]);
    *(int4*)(dst + c * 8) = u.v;
  }
}

// ---------------------------------------------------------------------------
// 6. Aggregate into basis space. WAVE per node (4 nodes/block), no LDS, no
//    barriers — round-0 structure (85 us measured). Lane owns cols
//    {4*lane..4*lane+3} x 4 bases. Changes vs round 0:
//      - float2 math -> v_pk_fma_f32 (VALU instrs/edge halved)
//      - edge loop unrolled x8 (8 gathers in flight; round 0 had 4 and sat
//        at 48% HBM / latency-bound)
//      - self block dropped (GEMM reads it from xb/h directly)
//    NOTE: nontemporal stores and persistent-wave queue were tried (round 1)
//    and regressed 2x (store-drain stalls; FETCH unchanged) — keep cached
//    stores and static one-wave-per-node mapping.
// ---------------------------------------------------------------------------
__device__ inline float2 pfma(float s, float2 a, float2 c) {
  c.x = fmaf(s, a.x, c.x);
  c.y = fmaf(s, a.y, c.y);
  return c;
}

__device__ inline void edge_fma(float2 acc[BASES][2], uint2 v, float4 w) {
  float2 a01 = make_float2(bfu_lo(v.x), bfu_hi(v.x));
  float2 a23 = make_float2(bfu_lo(v.y), bfu_hi(v.y));
  acc[0][0] = pfma(w.x, a01, acc[0][0]); acc[0][1] = pfma(w.x, a23, acc[0][1]);
  acc[1][0] = pfma(w.y, a01, acc[1][0]); acc[1][1] = pfma(w.y, a23, acc[1][1]);
  acc[2][0] = pfma(w.z, a01, acc[2][0]); acc[2][1] = pfma(w.z, a23, acc[2][1]);
  acc[3][0] = pfma(w.w, a01, acc[3][0]); acc[3][1] = pfma(w.w, a23, acc[3][1]);
}

__global__ __launch_bounds__(256) void aggregate_kernel(
    const unsigned* __restrict__ x2,   // bf16 features as uint pairs [N][128]
    const int* __restrict__ packed,
    const int* __restrict__ estart,
    const float4* __restrict__ wtab,   // [N*8] per-(node,rel) basis weights
    __hip_bfloat16* __restrict__ zA)   // [N][KZ]
{
  int tid = threadIdx.x;
  int wave = tid >> 6, lane = tid & 63;
  int n = blockIdx.x * 4 + wave;       // wave-uniform node
  const float4 wzero = make_float4(0.f, 0.f, 0.f, 0.f);

  float2 acc[BASES][2] = {};
  int s = estart[n], e = estart[n + 1];
  const float4* wt = wtab + (size_t)n * R_REL;

  for (int base = s; base < e; base += 8) {
    int rem = e - base;  // >= 1, wave-uniform
    int p[8];
#pragma unroll
    for (int k = 0; k < 8; k++)
      p[k] = packed[base + (rem > k ? k : 0)];
    // 8 independent gathers in flight
    uint2 v[8];
#pragma unroll
    for (int k = 0; k < 8; k++)
      v[k] = *(const uint2*)(x2 + (size_t)(p[k] & 0xFFFFF) * 128 + lane * 2);
    float4 w[8];
#pragma unroll
    for (int k = 0; k < 8; k++)
      w[k] = (rem > k) ? wt[p[k] >> 20] : wzero;   // k=0 always valid
#pragma unroll
    for (int k = 0; k < 8; k++)
      edge_fma(acc, v[k], w[k]);
  }

  // store: k = (4*lane+j)*4 + b = 16*lane + 4*j + b -> 32 contiguous bytes
  union { short s[8]; int4 v; } u0, u1;
#pragma unroll
  for (int b = 0; b < BASES; b++) {
    u0.s[b]     = (short)f2bu(acc[b][0].x);
    u0.s[4 + b] = (short)f2bu(acc[b][0].y);
    u1.s[b]     = (short)f2bu(acc[b][1].x);
    u1.s[4 + b] = (short)f2bu(acc[b][1].y);
  }
  __hip_bfloat16* zrow = zA + (size_t)n * KZ;
  *(int4*)(zrow + 16 * lane) = u0.v;
  *(int4*)(zrow + 16 * lane + 8) = u1.v;
}

// ---------------------------------------------------------------------------
// 7. GEMM: C[M,256] = A[M,1280](bf16) @ WT^T + bias. BM=128, BN=256 (full N,
//    A read once), 512 threads / 8 waves, BK=32, global_load_lds staging.
//    A is split: k<1024 from Az ([M][1024] aggregate), k>=1024 from Aself
//    ([M][256] node features) -- saves writing/reading the self copy.
// ---------------------------------------------------------------------------
#define BM 128
#define BN 256
#define BK 32

template <bool RELU, typename OutT>
__global__ __launch_bounds__(512) void gemm_kernel(
    const __hip_bfloat16* __restrict__ Az,     // [M, KZ]
    const __hip_bfloat16* __restrict__ Aself,  // [M, D]
    const __hip_bfloat16* __restrict__ Bt,     // [256, KT] (transposed weights)
    const float* __restrict__ bias, OutT* __restrict__ C, int M) {
  __shared__ __align__(16) __hip_bfloat16 As[BM * BK];  // 8 KB
  __shared__ __align__(16) __hip_bfloat16 Bs[BN * BK];  // 16 KB
  int tid = threadIdx.x;
  int m0 = blockIdx.x * BM;
  int wave = tid >> 6, lane = tid & 63;
  int wm = wave & 1, wn = wave >> 1;   // 2 x 4 wave grid, 64x64 tiles
  int l15 = lane & 15, quad = lane >> 4;

  // staging geometry: lane covers row = base + lane/4, col (lane&3)*8;
  // LDS dest = wave-uniform base + lane*16 B
  int colS = (lane & 3) * 8;
  int rowA = wave * 16 + (lane >> 2);           // 0..127 across 8 waves
  int grA  = min(m0 + rowA, M - 1);             // clamp; epilogue masks tail
  const __hip_bfloat16* gAz = Az + (size_t)grA * KZ + colS;
  const __hip_bfloat16* gAs = Aself + (size_t)grA * D + colS;
  const __hip_bfloat16* gB0 = Bt + (size_t)(wave * 32 + (lane >> 2)) * KT + colS;
  const __hip_bfloat16* gB1 = gB0 + 16 * KT;
  __hip_bfloat16* lA  = As + wave * 512;
  __hip_bfloat16* lB0 = Bs + wave * 1024;
  __hip_bfloat16* lB1 = Bs + wave * 1024 + 512;

  f32x4 acc[4][4] = {};

  for (int k0 = 0; k0 < KT; k0 += BK) {
    const __hip_bfloat16* srcA = (k0 < KZ) ? (gAz + k0) : (gAs + (k0 - KZ));
    gload_lds16(lA, srcA);
    gload_lds16(lB0, gB0 + k0);
    gload_lds16(lB1, gB1 + k0);
    __syncthreads();

    bf16x8 af[4], bfr[4];
#pragma unroll
    for (int mt = 0; mt < 4; mt++)
      af[mt] = *(const bf16x8*)(As + (wm * 64 + mt * 16 + l15) * BK + quad * 8);
#pragma unroll
    for (int nt = 0; nt < 4; nt++)
      bfr[nt] = *(const bf16x8*)(Bs + (wn * 64 + nt * 16 + l15) * BK + quad * 8);
#pragma unroll
    for (int mt = 0; mt < 4; mt++)
#pragma unroll
      for (int nt = 0; nt < 4; nt++)
        acc[mt][nt] = __builtin_amdgcn_mfma_f32_16x16x32_bf16(
            af[mt], bfr[nt], acc[mt][nt], 0, 0, 0);
    __syncthreads();
  }

  // epilogue: C/D layout col = lane&15, row = quad*4 + reg
#pragma unroll
  for (int nt = 0; nt < 4; nt++) {
    int cg = wn * 64 + nt * 16 + l15;
    float bv = bias[cg];
#pragma unroll
    for (int mt = 0; mt < 4; mt++) {
#pragma unroll
      for (int r = 0; r < 4; r++) {
        int rg = m0 + wm * 64 + mt * 16 + quad * 4 + r;
        if (rg < M) {
          float v = acc[mt][nt][r] + bv;
          if (RELU) v = fmaxf(v, 0.f);
          store_out(C + (size_t)rg * D + cg, v);
        }
      }
    }
  }
}

// ---------------------------------------------------------------------------
// Launch
// ---------------------------------------------------------------------------
static inline char* carve(char*& p, size_t bytes) {
  char* r = p;
  p += (bytes + 255) & ~(size_t)255;
  return r;
}

extern "C" void kernel_launch(void* const* d_in, const int* in_sizes, int n_in,
                              void* d_out, int out_size, void* d_ws,
                              size_t ws_size, hipStream_t stream) {
  const float* x      = (const float*)d_in[0];
  const int*   ei     = (const int*)d_in[1];
  const int*   et     = (const int*)d_in[2];
  const float* basis1 = (const float*)d_in[3];
  const float* comp1  = (const float*)d_in[4];
  const float* root1  = (const float*)d_in[5];
  const float* bias1  = (const float*)d_in[6];
  const float* basis2 = (const float*)d_in[7];
  const float* comp2  = (const float*)d_in[8];
  const float* root2  = (const float*)d_in[9];
  const float* bias2  = (const float*)d_in[10];
  float* out = (float*)d_out;

  char* ws = (char*)d_ws;
  int* cnt    = (int*)carve(ws, (size_t)N_NODES * R_REL * 4);
  int* estart = (int*)carve(ws, (size_t)(N_NODES + 1) * 4);
  int* cursor = (int*)carve(ws, (size_t)N_NODES * 4);
  int* bsum   = (int*)carve(ws, 256 * 4);
  int* boff   = (int*)carve(ws, 256 * 4);
  int* packed = (int*)carve(ws, (size_t)N_EDGES * 4);
  float4* wtab1 = (float4*)carve(ws, (size_t)N_NODES * R_REL * 16);
  float4* wtab2 = (float4*)carve(ws, (size_t)N_NODES * R_REL * 16);
  __hip_bfloat16* WT1 = (__hip_bfloat16*)carve(ws, (size_t)D * KT * 2);
  __hip_bfloat16* WT2 = (__hip_bfloat16*)carve(ws, (size_t)D * KT * 2);
  unsigned* xb = (unsigned*)carve(ws, (size_t)N_NODES * D * 2);   // bf16 x
  __hip_bfloat16* h = (__hip_bfloat16*)carve(ws, (size_t)N_NODES * D * 2);
  __hip_bfloat16* zA = (__hip_bfloat16*)carve(ws, (size_t)N_NODES * KZ * 2);

  const int NB = (N_NODES + 255) / 256;   // 196
  const int EB = (N_EDGES + 255) / 256;   // 3125
  const int CB = (N_NODES * 128 + 255) / 256;
  const int WB = (N_NODES * R_REL + 255) / 256;

  hipMemsetAsync(cnt, 0, (size_t)N_NODES * R_REL * 4, stream);
  hipMemsetAsync(cursor, 0, (size_t)N_NODES * 4, stream);

  count_kernel<<<EB, 256, 0, stream>>>(ei, et, cnt);
  scan_phaseA<<<NB, 256, 0, stream>>>(cnt, bsum);
  scan_phaseB<<<1, 256, 0, stream>>>(bsum, boff, estart, NB);
  scan_phaseC<<<NB, 256, 0, stream>>>(cnt, boff, estart);
  bucket_kernel<<<EB, 256, 0, stream>>>(ei, et, estart, cursor, packed);

  convert_kernel<<<CB, 256, 0, stream>>>(x, xb);
  winv_kernel<<<WB, 256, 0, stream>>>(cnt, comp1, wtab1);
  winv_kernel<<<WB, 256, 0, stream>>>(cnt, comp2, wtab2);
  make_w_kernel<<<KT / 64, 256, 0, stream>>>(basis1, root1, WT1);
  make_w_kernel<<<KT / 64, 256, 0, stream>>>(basis2, root2, WT2);

  dim3 ggrid((N_NODES + BM - 1) / BM, 1);  // 391 blocks, full N per block
  const int AB = (N_NODES + 3) / 4;        // 12500 blocks, wave per node

  // Layer 1
  aggregate_kernel<<<AB, 256, 0, stream>>>(xb, packed, estart, wtab1, zA);
  gemm_kernel<true, __hip_bfloat16><<<ggrid, 512, 0, stream>>>(
      zA, (const __hip_bfloat16*)xb, WT1, bias1, h, N_NODES);

  // Layer 2 (h is bf16 [N][256] — same packed-uint view as xb)
  aggregate_kernel<<<AB, 256, 0, stream>>>((const unsigned*)h, packed, estart,
                                           wtab2, zA);
  gemm_kernel<false, float><<<ggrid, 512, 0, stream>>>(
      zA, h, WT2, bias2, out, N_NODES);
}

// Round 3
// 468.434 us; speedup vs baseline: 1.5574x; 1.0489x over previous
//
#include <hip/hip_runtime.h>
#include <hip/hip_bf16.h>

// Problem constants (fixed by the reference)
constexpr int N_NODES = 50000;
constexpr int N_EDGES = 800000;
constexpr int R_REL   = 8;
constexpr int BASES   = 4;
constexpr int D       = 256;                 // DIN = DH = DOUT
constexpr int KZ      = BASES * D;           // 1024: basis-space aggregate
constexpr int KT      = KZ + D;              // 1280: + self block
constexpr int WSTRIDE = 16;                  // wtab float4s per node (r=8 is the
                                             // zero-weight dummy slot)
constexpr int DUMMY_P = 8 << 20;             // dummy edge: src=0, rel=8

// grid geometry
constexpr int EB  = (N_EDGES + 255) / 256;        // 3125
constexpr int NB  = (N_NODES + 255) / 256;        // 196
constexpr int CB  = (N_NODES * 128) / 256;        // 25000 (exact)
constexpr int WKB = KT / 64;                      // 20 (make_w blocks per layer)
constexpr int WB  = (N_NODES * WSTRIDE) / 256;    // 3125 (exact)
constexpr int CAP = N_EDGES + N_NODES * 8;        // 1,200,000 padded edge cap
constexpr int FB  = (CAP + 255) / 256;            // 4688

typedef __attribute__((ext_vector_type(8))) short bf16x8;
typedef __attribute__((ext_vector_type(4))) float f32x4;

__device__ inline float bfu_lo(unsigned u) { return __uint_as_float(u << 16); }
__device__ inline float bfu_hi(unsigned u) { return __uint_as_float(u & 0xFFFF0000u); }
__device__ inline unsigned short f2bu(float f) {
  __hip_bfloat16 h = __float2bfloat16(f);
  return *reinterpret_cast<unsigned short*>(&h);
}
__device__ inline void store_out(float* p, float v) { *p = v; }
__device__ inline void store_out(__hip_bfloat16* p, float v) { *p = __float2bfloat16(v); }

// async 16B global -> LDS (wave-uniform lds base + lane*16)
__device__ inline void gload_lds16(void* lds, const void* g) {
  __builtin_amdgcn_global_load_lds(
      (const __attribute__((address_space(1))) unsigned*)g,
      (__attribute__((address_space(3))) unsigned*)lds, 16, 0, 0);
}

// ---------------------------------------------------------------------------
// 1. Fused prep: [count | convert x->bf16 | make_w x2 | dummy-fill packed]
//    All jobs independent; range-split on blockIdx. 32 KB LDS (make_w tile)
//    caps residency at 5 blocks/CU = 20 waves — plenty for the streaming jobs.
// ---------------------------------------------------------------------------
__global__ __launch_bounds__(256) void prep_kernel(
    const int* __restrict__ ei, const int* __restrict__ et,
    int* __restrict__ cnt,
    const float* __restrict__ x, unsigned* __restrict__ x2,
    const float* __restrict__ basis1, const float* __restrict__ root1,
    __hip_bfloat16* __restrict__ WT1,
    const float* __restrict__ basis2, const float* __restrict__ root2,
    __hip_bfloat16* __restrict__ WT2,
    int* __restrict__ packed) {
  __shared__ __hip_bfloat16 tile[64][256];
  int bid = blockIdx.x;
  int tid = threadIdx.x;

  if (bid < EB) {                       // --- count ---
    int e = bid * 256 + tid;
    if (e < N_EDGES) {
      int dst = ei[N_EDGES + e];
      atomicAdd(&cnt[dst * R_REL + et[e]], 1);
    }
    return;
  }
  bid -= EB;
  if (bid < CB) {                       // --- convert x (fp32) -> bf16 pairs ---
    int idx = bid * 256 + tid;          // exact: CB*256 == N*128
    float2 v = *(const float2*)(x + (size_t)idx * 2);
    x2[idx] = (unsigned)f2bu(v.x) | ((unsigned)f2bu(v.y) << 16);
    return;
  }
  bid -= CB;
  if (bid < 2 * WKB) {                  // --- weight build (both layers) ---
    const float* basis = (bid < WKB) ? basis1 : basis2;
    const float* root  = (bid < WKB) ? root1 : root2;
    __hip_bfloat16* WT = (bid < WKB) ? WT1 : WT2;
    int wb = (bid < WKB) ? bid : bid - WKB;
    int k0 = wb * 64;
#pragma unroll 4
    for (int r = 0; r < 64; r++) {
      int k = k0 + r;
      const float* srow = (k < KZ)
          ? basis + ((size_t)(k & 3) * D + (k >> 2)) * D
          : root + (size_t)(k - KZ) * D;
      tile[r][tid] = __float2bfloat16(srow[tid]);
    }
    __syncthreads();
    __hip_bfloat16* dst = WT + (size_t)tid * KT + k0;
#pragma unroll
    for (int c = 0; c < 8; c++) {
      union { short s[8]; int4 v; } u;
#pragma unroll
      for (int r = 0; r < 8; r++)
        u.s[r] = *reinterpret_cast<short*>(&tile[c * 8 + r][tid]);
      *(int4*)(dst + c * 8) = u.v;
    }
    return;
  }
  bid -= 2 * WKB;
  {                                     // --- dummy-fill packed ---
    int i = bid * 256 + tid;
    if (i < CAP) packed[i] = DUMMY_P;
  }
}

// ---------------------------------------------------------------------------
// 2. scanA (block sums of PADDED degree) fused with winv x2
// ---------------------------------------------------------------------------
__global__ __launch_bounds__(256) void scanA_winv_kernel(
    const int* __restrict__ cnt, int* __restrict__ bsum,
    const float* __restrict__ comp1, float4* __restrict__ wtab1,
    const float* __restrict__ comp2, float4* __restrict__ wtab2) {
  __shared__ int sd[256];
  int bid = blockIdx.x;
  int tid = threadIdx.x;
  if (bid < NB) {                       // --- scanA on padded degree ---
    int n = bid * 256 + tid;
    int d = 0;
    if (n < N_NODES) {
#pragma unroll
      for (int r = 0; r < R_REL; r++) d += cnt[n * R_REL + r];
      d = (d + 7) & ~7;                 // pad each bucket to x8
    }
    sd[tid] = d;
    __syncthreads();
    for (int off = 128; off > 0; off >>= 1) {
      if (tid < off) sd[tid] += sd[tid + off];
      __syncthreads();
    }
    if (tid == 0) bsum[bid] = sd[0];
    return;
  }
  bid -= NB;
  {                                     // --- winv (both layers) ---
    const float* comp = (bid < WB) ? comp1 : comp2;
    float4* wtab = (bid < WB) ? wtab1 : wtab2;
    int lb = (bid < WB) ? bid : bid - WB;
    int idx = lb * 256 + tid;           // exact: WB*256 == N*WSTRIDE
    int r = idx & (WSTRIDE - 1);
    int n = idx >> 4;
    float4 w = make_float4(0.f, 0.f, 0.f, 0.f);
    if (r < R_REL) {
      int c = cnt[n * R_REL + r];
      float inv = 1.0f / (float)(c > 0 ? c : 1);
      w.x = comp[r * BASES + 0] * inv;
      w.y = comp[r * BASES + 1] * inv;
      w.z = comp[r * BASES + 2] * inv;
      w.w = comp[r * BASES + 3] * inv;
    }
    wtab[idx] = w;
  }
}

// ---------------------------------------------------------------------------
// 3. Scan phases B/C on padded degree. scanC also zeroes cursor.
// ---------------------------------------------------------------------------
__global__ __launch_bounds__(256) void scan_phaseB(
    const int* __restrict__ bsum, int* __restrict__ boff,
    int* __restrict__ estart) {
  __shared__ int sd[256];
  int tid = threadIdx.x;
  int v = (tid < NB) ? bsum[tid] : 0;
  sd[tid] = v;
  __syncthreads();
  for (int off = 1; off < 256; off <<= 1) {
    int t = (tid >= off) ? sd[tid - off] : 0;
    __syncthreads();
    sd[tid] += t;
    __syncthreads();
  }
  if (tid < NB) boff[tid] = sd[tid] - v;
  if (tid == NB - 1) estart[N_NODES] = sd[tid];   // total padded edges
}

__global__ __launch_bounds__(256) void scan_phaseC(
    const int* __restrict__ cnt, const int* __restrict__ boff,
    int* __restrict__ estart, int* __restrict__ cursor) {
  __shared__ int sd[256];
  int tid = threadIdx.x;
  int n = blockIdx.x * 256 + tid;
  int d = 0;
  if (n < N_NODES) {
#pragma unroll
    for (int r = 0; r < R_REL; r++) d += cnt[n * R_REL + r];
    d = (d + 7) & ~7;
  }
  sd[tid] = d;
  __syncthreads();
  for (int off = 1; off < 256; off <<= 1) {
    int t = (tid >= off) ? sd[tid - off] : 0;
    __syncthreads();
    sd[tid] += t;
    __syncthreads();
  }
  if (n < N_NODES) {
    estart[n] = boff[blockIdx.x] + sd[tid] - d;
    cursor[n] = 0;
  }
}

// ---------------------------------------------------------------------------
// 4. Bucket edges by dst into padded layout: packed = src | (rt << 20).
//    Tail of each bucket stays DUMMY_P (prefilled).
// ---------------------------------------------------------------------------
__global__ __launch_bounds__(256) void bucket_kernel(
    const int* __restrict__ ei, const int* __restrict__ et,
    const int* __restrict__ estart, int* __restrict__ cursor,
    int* __restrict__ packed) {
  int e = blockIdx.x * 256 + threadIdx.x;
  if (e < N_EDGES) {
    int src = ei[e];
    int dst = ei[N_EDGES + e];
    int rt  = et[e];
    int pos = estart[dst] + atomicAdd(&cursor[dst], 1);
    packed[pos] = src | (rt << 20);
  }
}

// ---------------------------------------------------------------------------
// 5. Aggregate into basis space. WAVE per node (4/block). All wave-uniform
//    work (edge list, weights, row bases) forced onto the SCALAR pipe via
//    readfirstlane; buckets padded to x8 so the inner loop is branch- and
//    mask-free. Per-edge vector work: 1 global_load_dwordx2 (loop-invariant
//    voff), 4 unpack ops, 8 pk-fma.
// ---------------------------------------------------------------------------
__device__ inline float2 pfma(float s, float2 a, float2 c) {
  c.x = fmaf(s, a.x, c.x);
  c.y = fmaf(s, a.y, c.y);
  return c;
}

__device__ inline void edge_fma(float2 acc[BASES][2], uint2 v, float4 w) {
  float2 a01 = make_float2(bfu_lo(v.x), bfu_hi(v.x));
  float2 a23 = make_float2(bfu_lo(v.y), bfu_hi(v.y));
  acc[0][0] = pfma(w.x, a01, acc[0][0]); acc[0][1] = pfma(w.x, a23, acc[0][1]);
  acc[1][0] = pfma(w.y, a01, acc[1][0]); acc[1][1] = pfma(w.y, a23, acc[1][1]);
  acc[2][0] = pfma(w.z, a01, acc[2][0]); acc[2][1] = pfma(w.z, a23, acc[2][1]);
  acc[3][0] = pfma(w.w, a01, acc[3][0]); acc[3][1] = pfma(w.w, a23, acc[3][1]);
}

__global__ __launch_bounds__(256) void aggregate_kernel(
    const unsigned* __restrict__ x2,   // bf16 features as uint pairs [N][128]
    const int* __restrict__ packed,    // padded-x8 buckets
    const int* __restrict__ estart,    // padded offsets
    const float4* __restrict__ wtab,   // [N*16]; slot 8 = zero (dummy)
    __hip_bfloat16* __restrict__ zA)   // [N][KZ]
{
  int tid = threadIdx.x;
  int lane = tid & 63;
  int n = __builtin_amdgcn_readfirstlane(blockIdx.x * 4 + (tid >> 6));
  int s = __builtin_amdgcn_readfirstlane(estart[n]);
  int e = __builtin_amdgcn_readfirstlane(estart[n + 1]);
  const int voff = lane * 2;                         // uint index within row
  const float4* wt = wtab + (size_t)n * WSTRIDE;

  float2 acc[BASES][2] = {};

  for (int base = s; base < e; base += 8) {
    int4 q0 = *(const int4*)(packed + base);         // uniform addr -> s_load
    int4 q1 = *(const int4*)(packed + base + 4);
    int p0 = __builtin_amdgcn_readfirstlane(q0.x);
    int p1 = __builtin_amdgcn_readfirstlane(q0.y);
    int p2 = __builtin_amdgcn_readfirstlane(q0.z);
    int p3 = __builtin_amdgcn_readfirstlane(q0.w);
    int p4 = __builtin_amdgcn_readfirstlane(q1.x);
    int p5 = __builtin_amdgcn_readfirstlane(q1.y);
    int p6 = __builtin_amdgcn_readfirstlane(q1.z);
    int p7 = __builtin_amdgcn_readfirstlane(q1.w);
    // SGPR row bases; vector part is just base+voff
    const unsigned* r0 = x2 + ((size_t)(p0 & 0xFFFFF) << 7);
    const unsigned* r1 = x2 + ((size_t)(p1 & 0xFFFFF) << 7);
    const unsigned* r2 = x2 + ((size_t)(p2 & 0xFFFFF) << 7);
    const unsigned* r3 = x2 + ((size_t)(p3 & 0xFFFFF) << 7);
    const unsigned* r4 = x2 + ((size_t)(p4 & 0xFFFFF) << 7);
    const unsigned* r5 = x2 + ((size_t)(p5 & 0xFFFFF) << 7);
    const unsigned* r6 = x2 + ((size_t)(p6 & 0xFFFFF) << 7);
    const unsigned* r7 = x2 + ((size_t)(p7 & 0xFFFFF) << 7);
    uint2 v0 = *(const uint2*)(r0 + voff);
    uint2 v1 = *(const uint2*)(r1 + voff);
    uint2 v2 = *(const uint2*)(r2 + voff);
    uint2 v3 = *(const uint2*)(r3 + voff);
    uint2 v4 = *(const uint2*)(r4 + voff);
    uint2 v5 = *(const uint2*)(r5 + voff);
    uint2 v6 = *(const uint2*)(r6 + voff);
    uint2 v7 = *(const uint2*)(r7 + voff);
    float4 w0 = wt[p0 >> 20];                        // uniform -> s_load_x4
    float4 w1 = wt[p1 >> 20];
    float4 w2 = wt[p2 >> 20];
    float4 w3 = wt[p3 >> 20];
    float4 w4 = wt[p4 >> 20];
    float4 w5 = wt[p5 >> 20];
    float4 w6 = wt[p6 >> 20];
    float4 w7 = wt[p7 >> 20];
    edge_fma(acc, v0, w0);
    edge_fma(acc, v1, w1);
    edge_fma(acc, v2, w2);
    edge_fma(acc, v3, w3);
    edge_fma(acc, v4, w4);
    edge_fma(acc, v5, w5);
    edge_fma(acc, v6, w6);
    edge_fma(acc, v7, w7);
  }

  // store: k = (4*lane+j)*4 + b = 16*lane + 4*j + b -> 32 contiguous bytes
  union { short s[8]; int4 v; } u0, u1;
#pragma unroll
  for (int b = 0; b < BASES; b++) {
    u0.s[b]     = (short)f2bu(acc[b][0].x);
    u0.s[4 + b] = (short)f2bu(acc[b][0].y);
    u1.s[b]     = (short)f2bu(acc[b][1].x);
    u1.s[4 + b] = (short)f2bu(acc[b][1].y);
  }
  __hip_bfloat16* zrow = zA + (size_t)n * KZ;
  *(int4*)(zrow + 16 * lane) = u0.v;
  *(int4*)(zrow + 16 * lane + 8) = u1.v;
}

// ---------------------------------------------------------------------------
// 6. GEMM: C[M,256] = A[M,1280](bf16) @ WT^T + bias. BM=128, BN=256 (full N,
//    A read once), 512 threads / 8 waves, BK=32, global_load_lds staging.
//    A split: k<1024 from Az ([M][1024] aggregate), k>=1024 from Aself.
// ---------------------------------------------------------------------------
#define BM 128
#define BN 256
#define BK 32

template <bool RELU, typename OutT>
__global__ __launch_bounds__(512) void gemm_kernel(
    const __hip_bfloat16* __restrict__ Az,     // [M, KZ]
    const __hip_bfloat16* __restrict__ Aself,  // [M, D]
    const __hip_bfloat16* __restrict__ Bt,     // [256, KT]
    const float* __restrict__ bias, OutT* __restrict__ C, int M) {
  __shared__ __align__(16) __hip_bfloat16 As[BM * BK];  // 8 KB
  __shared__ __align__(16) __hip_bfloat16 Bs[BN * BK];  // 16 KB
  int tid = threadIdx.x;
  int m0 = blockIdx.x * BM;
  int wave = tid >> 6, lane = tid & 63;
  int wm = wave & 1, wn = wave >> 1;   // 2 x 4 wave grid, 64x64 tiles
  int l15 = lane & 15, quad = lane >> 4;

  int colS = (lane & 3) * 8;
  int rowA = wave * 16 + (lane >> 2);           // 0..127 across 8 waves
  int grA  = min(m0 + rowA, M - 1);             // clamp; epilogue masks tail
  const __hip_bfloat16* gAz = Az + (size_t)grA * KZ + colS;
  const __hip_bfloat16* gAs = Aself + (size_t)grA * D + colS;
  const __hip_bfloat16* gB0 = Bt + (size_t)(wave * 32 + (lane >> 2)) * KT + colS;
  const __hip_bfloat16* gB1 = gB0 + 16 * KT;
  __hip_bfloat16* lA  = As + wave * 512;
  __hip_bfloat16* lB0 = Bs + wave * 1024;
  __hip_bfloat16* lB1 = Bs + wave * 1024 + 512;

  f32x4 acc[4][4] = {};

  for (int k0 = 0; k0 < KT; k0 += BK) {
    const __hip_bfloat16* srcA = (k0 < KZ) ? (gAz + k0) : (gAs + (k0 - KZ));
    gload_lds16(lA, srcA);
    gload_lds16(lB0, gB0 + k0);
    gload_lds16(lB1, gB1 + k0);
    __syncthreads();

    bf16x8 af[4], bfr[4];
#pragma unroll
    for (int mt = 0; mt < 4; mt++)
      af[mt] = *(const bf16x8*)(As + (wm * 64 + mt * 16 + l15) * BK + quad * 8);
#pragma unroll
    for (int nt = 0; nt < 4; nt++)
      bfr[nt] = *(const bf16x8*)(Bs + (wn * 64 + nt * 16 + l15) * BK + quad * 8);
#pragma unroll
    for (int mt = 0; mt < 4; mt++)
#pragma unroll
      for (int nt = 0; nt < 4; nt++)
        acc[mt][nt] = __builtin_amdgcn_mfma_f32_16x16x32_bf16(
            af[mt], bfr[nt], acc[mt][nt], 0, 0, 0);
    __syncthreads();
  }

  // epilogue: C/D layout col = lane&15, row = quad*4 + reg
#pragma unroll
  for (int nt = 0; nt < 4; nt++) {
    int cg = wn * 64 + nt * 16 + l15;
    float bv = bias[cg];
#pragma unroll
    for (int mt = 0; mt < 4; mt++) {
#pragma unroll
      for (int r = 0; r < 4; r++) {
        int rg = m0 + wm * 64 + mt * 16 + quad * 4 + r;
        if (rg < M) {
          float v = acc[mt][nt][r] + bv;
          if (RELU) v = fmaxf(v, 0.f);
          store_out(C + (size_t)rg * D + cg, v);
        }
      }
    }
  }
}

// ---------------------------------------------------------------------------
// Launch
// ---------------------------------------------------------------------------
static inline char* carve(char*& p, size_t bytes) {
  char* r = p;
  p += (bytes + 255) & ~(size_t)255;
  return r;
}

extern "C" void kernel_launch(void* const* d_in, const int* in_sizes, int n_in,
                              void* d_out, int out_size, void* d_ws,
                              size_t ws_size, hipStream_t stream) {
  const float* x      = (const float*)d_in[0];
  const int*   ei     = (const int*)d_in[1];
  const int*   et     = (const int*)d_in[2];
  const float* basis1 = (const float*)d_in[3];
  const float* comp1  = (const float*)d_in[4];
  const float* root1  = (const float*)d_in[5];
  const float* bias1  = (const float*)d_in[6];
  const float* basis2 = (const float*)d_in[7];
  const float* comp2  = (const float*)d_in[8];
  const float* root2  = (const float*)d_in[9];
  const float* bias2  = (const float*)d_in[10];
  float* out = (float*)d_out;

  char* ws = (char*)d_ws;
  int* cnt    = (int*)carve(ws, (size_t)N_NODES * R_REL * 4);
  int* estart = (int*)carve(ws, (size_t)(N_NODES + 1) * 4);
  int* cursor = (int*)carve(ws, (size_t)N_NODES * 4);
  int* bsum   = (int*)carve(ws, 256 * 4);
  int* boff   = (int*)carve(ws, 256 * 4);
  int* packed = (int*)carve(ws, (size_t)CAP * 4);
  float4* wtab1 = (float4*)carve(ws, (size_t)N_NODES * WSTRIDE * 16);
  float4* wtab2 = (float4*)carve(ws, (size_t)N_NODES * WSTRIDE * 16);
  __hip_bfloat16* WT1 = (__hip_bfloat16*)carve(ws, (size_t)D * KT * 2);
  __hip_bfloat16* WT2 = (__hip_bfloat16*)carve(ws, (size_t)D * KT * 2);
  unsigned* xb = (unsigned*)carve(ws, (size_t)N_NODES * D * 2);   // bf16 x
  __hip_bfloat16* h = (__hip_bfloat16*)carve(ws, (size_t)N_NODES * D * 2);
  __hip_bfloat16* zA = (__hip_bfloat16*)carve(ws, (size_t)N_NODES * KZ * 2);

  hipMemsetAsync(cnt, 0, (size_t)N_NODES * R_REL * 4, stream);

  prep_kernel<<<EB + CB + 2 * WKB + FB, 256, 0, stream>>>(
      ei, et, cnt, x, xb, basis1, root1, WT1, basis2, root2, WT2, packed);
  scanA_winv_kernel<<<NB + 2 * WB, 256, 0, stream>>>(cnt, bsum, comp1, wtab1,
                                                     comp2, wtab2);
  scan_phaseB<<<1, 256, 0, stream>>>(bsum, boff, estart);
  scan_phaseC<<<NB, 256, 0, stream>>>(cnt, boff, estart, cursor);
  bucket_kernel<<<EB, 256, 0, stream>>>(ei, et, estart, cursor, packed);

  dim3 ggrid((N_NODES + BM - 1) / BM, 1);  // 391 blocks, full N per block
  const int AB = (N_NODES + 3) / 4;        // 12500 blocks, wave per node

  // Layer 1
  aggregate_kernel<<<AB, 256, 0, stream>>>(xb, packed, estart, wtab1, zA);
  gemm_kernel<true, __hip_bfloat16><<<ggrid, 512, 0, stream>>>(
      zA, (const __hip_bfloat16*)xb, WT1, bias1, h, N_NODES);

  // Layer 2 (h is bf16 [N][256] — same packed-uint view as xb)
  aggregate_kernel<<<AB, 256, 0, stream>>>((const unsigned*)h, packed, estart,
                                           wtab2, zA);
  gemm_kernel<false, float><<<ggrid, 512, 0, stream>>>(
      zA, h, WT2, bias2, out, N_NODES);
}